// Round 5
// baseline (944.822 us; speedup 1.0000x reference)
//
#include <hip/hip_runtime.h>

// Sinkhorn [B=32, N=1024, M=1024], 15 alternating normalizations, eps=1e-4.
// Factorized: s_k = diag(r_k) * S0 * diag(c_k); each iteration is one matvec
// with the constant S0 + a tiny vector update folded into the consumer.
// Pass 0 emits an fp16 copy of S0 into d_ws; the 14 middle passes read the
// fp16 copy (half traffic). Final scale uses fp32 S0 (quantization enters
// only via the factor vectors; est. output rel err ~1e-5). Falls back to
// pure fp32 if ws_size can't hold the 64 MiB copy.
//
// Block->batch mapping: b = bid % 32 so every block of batch b lands on
// XCD b%8 in every pass (L2 reuse across passes; correctness-neutral).

#define EPSF 1e-4f
constexpr int B_      = 32;
constexpr int N_      = 1024;
constexpr int M_      = 1024;
constexpr int ICHUNK  = 32;            // rows per block
constexpr int NCHUNKS = N_ / ICHUNK;   // 32
constexpr int THREADS = 256;

typedef _Float16 half4v __attribute__((ext_vector_type(4)));
typedef _Float16 half8v __attribute__((ext_vector_type(8)));
typedef float    f32x4  __attribute__((ext_vector_type(4)));

// ===========================================================================
// k=0 (colsum, r=1): u0[b][j] = sum_i s0[b][i][j]; also emit fp16 copy.
// ===========================================================================
__global__ __launch_bounds__(THREADS)
void colsum_conv_kernel(const float* __restrict__ s0,
                        _Float16* __restrict__ sh,
                        float* __restrict__ uacc,
                        float* __restrict__ accZero)
{
    const int bid = blockIdx.x, t = threadIdx.x;
    const int b = bid % B_, chunk = bid / B_;
    const int i0 = chunk * ICHUNK;

    if (bid < B_)   // zero NEXT kernel's accumulator (stream-ordered)
        reinterpret_cast<float4*>(accZero)[bid * THREADS + t] =
            make_float4(0.f, 0.f, 0.f, 0.f);

    const size_t base4 = ((size_t)b * N_ + i0) * (M_ / 4);
    const float4* s4 = reinterpret_cast<const float4*>(s0) + base4;
    half4v*       o4 = reinterpret_cast<half4v*>(sh) + base4;

    float4 acc = make_float4(0.f, 0.f, 0.f, 0.f);
    #pragma unroll 4
    for (int i = 0; i < ICHUNK; ++i) {
        const float4 sv = s4[(size_t)i * (M_ / 4) + t];
        acc.x += sv.x; acc.y += sv.y; acc.z += sv.z; acc.w += sv.w;
        half4v h;
        h[0] = (_Float16)sv.x; h[1] = (_Float16)sv.y;
        h[2] = (_Float16)sv.z; h[3] = (_Float16)sv.w;
        o4[(size_t)i * (M_ / 4) + t] = h;
    }
    float* up = uacc + b * M_ + t * 4;
    atomicAdd(up + 0, acc.x); atomicAdd(up + 1, acc.y);
    atomicAdd(up + 2, acc.z); atomicAdd(up + 3, acc.w);
}

// ===========================================================================
// colsum fp16 (even k>=2): u[b][j] += sum_i r_k[b][i] * sh[b][i][j]
//   r_k = rp/(rp*v+eps); mode 1: rp=1 (k=2), mode 2: rp=rprev.
// Block = (batch, 32-row chunk); 2 rowgroups x 128 colthreads x 8 cols,
// half8 loads (16 B/lane). Atomic combine (64 adds/column, negligible).
// ===========================================================================
__global__ __launch_bounds__(THREADS)
void colsum_f16_kernel(const _Float16* __restrict__ sh,
                       const float* __restrict__ rprev,
                       const float* __restrict__ vacc,
                       float* __restrict__ rout,
                       float* __restrict__ uacc,
                       float* __restrict__ accZero,
                       int mode)
{
    __shared__ float rS[ICHUNK];
    const int bid = blockIdx.x, t = threadIdx.x;
    const int b = bid % B_, chunk = bid / B_;
    const int i0 = chunk * ICHUNK;

    if (bid < B_)
        reinterpret_cast<float4*>(accZero)[bid * THREADS + t] =
            make_float4(0.f, 0.f, 0.f, 0.f);

    if (t < ICHUNK) {
        const int gi = b * N_ + i0 + t;
        const float v  = vacc[gi];
        const float rp = (mode == 1) ? 1.0f : rprev[gi];
        const float r  = rp / (rp * v + EPSF);
        rout[gi] = r;        // (b,i) owned exclusively by this block
        rS[t] = r;
    }
    __syncthreads();

    const int g  = t >> 7;          // rowgroup 0/1 (wave-uniform)
    const int ct = t & 127;         // column thread: cols 8*ct..8*ct+7
    const int ib = g * (ICHUNK / 2);
    const half8v* srow = reinterpret_cast<const half8v*>(sh)
                       + ((size_t)b * N_ + i0 + ib) * (M_ / 8);
    float acc[8] = {0.f,0.f,0.f,0.f,0.f,0.f,0.f,0.f};
    #pragma unroll 4
    for (int i = 0; i < ICHUNK / 2; ++i) {
        const float r = rS[ib + i];              // wave-uniform broadcast
        const half8v s8 = srow[(size_t)i * (M_ / 8) + ct];
        #pragma unroll
        for (int e = 0; e < 8; ++e) acc[e] += r * (float)s8[e];
    }
    float* up = uacc + b * M_ + ct * 8;
    #pragma unroll
    for (int e = 0; e < 8; ++e) atomicAdd(up + e, acc[e]);
}

// ===========================================================================
// rowsum fp16 (odd k): v[b][i] = sum_j sh[b][i][j] * c_k[b][j]
//   c_k = cp/(cp*u+eps); mode 1: cp=1 (k=1), mode 2: cp=cprev.
// One wave per row, half8 loads, c fragments hoisted to registers,
// 64-lane shuffle reduce, plain store (exclusive per (b,i)).
// ===========================================================================
__global__ __launch_bounds__(THREADS)
void rowsum_f16_kernel(const _Float16* __restrict__ sh,
                       const float* __restrict__ cprev,
                       const float* __restrict__ uacc,
                       float* __restrict__ cout,
                       float* __restrict__ vacc,
                       float* __restrict__ accZero,
                       int mode)
{
    __shared__ float cS[M_];
    const int bid = blockIdx.x, t = threadIdx.x;
    const int b = bid % B_, chunk = bid / B_;
    const int i0 = chunk * ICHUNK;

    if (bid < B_)
        reinterpret_cast<float4*>(accZero)[bid * THREADS + t] =
            make_float4(0.f, 0.f, 0.f, 0.f);

    {
        const float4 u4 = reinterpret_cast<const float4*>(uacc + b * M_)[t];
        float4 cp4 = make_float4(1.f, 1.f, 1.f, 1.f);
        if (mode != 1)
            cp4 = reinterpret_cast<const float4*>(cprev + b * M_)[t];
        float4 c4;
        c4.x = cp4.x / (cp4.x * u4.x + EPSF);
        c4.y = cp4.y / (cp4.y * u4.y + EPSF);
        c4.z = cp4.z / (cp4.z * u4.z + EPSF);
        c4.w = cp4.w / (cp4.w * u4.w + EPSF);
        reinterpret_cast<float4*>(cS)[t] = c4;
        if (chunk == 0)   // one block per batch persists c_k
            reinterpret_cast<float4*>(cout + b * M_)[t] = c4;
    }
    __syncthreads();

    const int wave = t >> 6, lane = t & 63;
    constexpr int RPW = ICHUNK / 4;   // 8 rows per wave

    // hoist c fragments (row-invariant): cols 8*(q*64+lane)..+7
    const float4* cS4 = reinterpret_cast<const float4*>(cS);
    float4 creg[2][2];
    #pragma unroll
    for (int q = 0; q < 2; ++q) {
        creg[q][0] = cS4[2 * (q * 64 + lane)];
        creg[q][1] = cS4[2 * (q * 64 + lane) + 1];
    }

    const half8v* sbase =
        reinterpret_cast<const half8v*>(sh) + (size_t)b * N_ * (M_ / 8);
    #pragma unroll 2
    for (int rw = 0; rw < RPW; ++rw) {
        const int i = i0 + wave * RPW + rw;
        const half8v* row = sbase + (size_t)i * (M_ / 8);
        float sum = 0.f;
        #pragma unroll
        for (int q = 0; q < 2; ++q) {
            const half8v s8 = row[q * 64 + lane];
            sum += (float)s8[0] * creg[q][0].x + (float)s8[1] * creg[q][0].y
                 + (float)s8[2] * creg[q][0].z + (float)s8[3] * creg[q][0].w
                 + (float)s8[4] * creg[q][1].x + (float)s8[5] * creg[q][1].y
                 + (float)s8[6] * creg[q][1].z + (float)s8[7] * creg[q][1].w;
        }
        #pragma unroll
        for (int off = 32; off > 0; off >>= 1)
            sum += __shfl_down(sum, off, 64);
        if (lane == 0)
            vacc[b * N_ + i] = sum;
    }
}

// ===========================================================================
// fp32 fallback kernels (used only if ws_size can't hold the fp16 copy)
// ===========================================================================
__global__ __launch_bounds__(THREADS)
void colsum_kernel(const float* __restrict__ s0,
                   const float* __restrict__ rprev,
                   const float* __restrict__ vacc,
                   float* __restrict__ rout,
                   float* __restrict__ uacc,
                   float* __restrict__ accZero,
                   int mode)
{
    __shared__ float rS[ICHUNK];
    const int bid = blockIdx.x, t = threadIdx.x;
    const int b = bid % B_, chunk = bid / B_;
    const int i0 = chunk * ICHUNK;

    if (bid < B_)
        reinterpret_cast<float4*>(accZero)[bid * THREADS + t] =
            make_float4(0.f, 0.f, 0.f, 0.f);

    if (t < ICHUNK) {
        const int gi = b * N_ + i0 + t;
        float r;
        if (mode == 0) r = 1.0f;
        else {
            const float v  = vacc[gi];
            const float rp = (mode == 1) ? 1.0f : rprev[gi];
            r = rp / (rp * v + EPSF);
            rout[gi] = r;
        }
        rS[t] = r;
    }
    __syncthreads();

    const float4* srow =
        reinterpret_cast<const float4*>(s0) + ((size_t)b * N_ + i0) * (M_ / 4);
    float4 acc = make_float4(0.f, 0.f, 0.f, 0.f);
    #pragma unroll 8
    for (int i = 0; i < ICHUNK; ++i) {
        const float  r  = rS[i];
        const float4 sv = srow[(size_t)i * (M_ / 4) + t];
        acc.x += r * sv.x; acc.y += r * sv.y;
        acc.z += r * sv.z; acc.w += r * sv.w;
    }
    float* up = uacc + b * M_ + t * 4;
    atomicAdd(up + 0, acc.x); atomicAdd(up + 1, acc.y);
    atomicAdd(up + 2, acc.z); atomicAdd(up + 3, acc.w);
}

__global__ __launch_bounds__(THREADS)
void rowsum_kernel(const float* __restrict__ s0,
                   const float* __restrict__ cprev,
                   const float* __restrict__ uacc,
                   float* __restrict__ cout,
                   float* __restrict__ vacc,
                   float* __restrict__ accZero,
                   int mode)
{
    __shared__ float cS[M_];
    const int bid = blockIdx.x, t = threadIdx.x;
    const int b = bid % B_, chunk = bid / B_;
    const int i0 = chunk * ICHUNK;

    if (bid < B_)
        reinterpret_cast<float4*>(accZero)[bid * THREADS + t] =
            make_float4(0.f, 0.f, 0.f, 0.f);

    {
        const float4 u4 = reinterpret_cast<const float4*>(uacc + b * M_)[t];
        float4 cp4 = make_float4(1.f, 1.f, 1.f, 1.f);
        if (mode != 1)
            cp4 = reinterpret_cast<const float4*>(cprev + b * M_)[t];
        float4 c4;
        c4.x = cp4.x / (cp4.x * u4.x + EPSF);
        c4.y = cp4.y / (cp4.y * u4.y + EPSF);
        c4.z = cp4.z / (cp4.z * u4.z + EPSF);
        c4.w = cp4.w / (cp4.w * u4.w + EPSF);
        reinterpret_cast<float4*>(cS)[t] = c4;
        if (chunk == 0)
            reinterpret_cast<float4*>(cout + b * M_)[t] = c4;
    }
    __syncthreads();

    const int wave = t >> 6, lane = t & 63;
    constexpr int ROWS_PER_WAVE = ICHUNK / 4;
    float4 creg[4];
    #pragma unroll
    for (int q = 0; q < 4; ++q)
        creg[q] = reinterpret_cast<float4*>(cS)[q * 64 + lane];

    const float4* sbase =
        reinterpret_cast<const float4*>(s0) + (size_t)b * N_ * (M_ / 4);
    for (int rw = 0; rw < ROWS_PER_WAVE; ++rw) {
        const int i = i0 + wave * ROWS_PER_WAVE + rw;
        const float4* row = sbase + (size_t)i * (M_ / 4);
        float sum = 0.f;
        #pragma unroll
        for (int q = 0; q < 4; ++q) {
            const float4 sv = row[q * 64 + lane];
            sum += sv.x * creg[q].x + sv.y * creg[q].y +
                   sv.z * creg[q].z + sv.w * creg[q].w;
        }
        #pragma unroll
        for (int off = 32; off > 0; off >>= 1)
            sum += __shfl_down(sum, off, 64);
        if (lane == 0)
            vacc[b * N_ + i] = sum;
    }
}

// ===========================================================================
// final: out[b][i][j] = r14[b][i] * s0[b][i][j] * c15[b][j]  (fp32 S0)
//   c15 computed per-thread from c13 and u14. NT stores (out never re-read)
//   via ext_vector f32x4 — __builtin_nontemporal_store needs a true vector
//   type, not HIP's float4 class.
// ===========================================================================
__global__ __launch_bounds__(THREADS)
void final_kernel(const float* __restrict__ s0,
                  const float* __restrict__ cprev,   // c13
                  const float* __restrict__ uacc,    // u14
                  const float* __restrict__ rbuf,    // r14
                  float* __restrict__ out)
{
    __shared__ float rS[ICHUNK];
    const int bid = blockIdx.x, t = threadIdx.x;
    const int b = bid % B_, chunk = bid / B_;
    const int i0 = chunk * ICHUNK;

    const f32x4 u4  = reinterpret_cast<const f32x4*>(uacc  + b * M_)[t];
    const f32x4 cp4 = reinterpret_cast<const f32x4*>(cprev + b * M_)[t];
    f32x4 c4;
    c4.x = cp4.x / (cp4.x * u4.x + EPSF);
    c4.y = cp4.y / (cp4.y * u4.y + EPSF);
    c4.z = cp4.z / (cp4.z * u4.z + EPSF);
    c4.w = cp4.w / (cp4.w * u4.w + EPSF);

    if (t < ICHUNK) rS[t] = rbuf[b * N_ + i0 + t];
    __syncthreads();

    const size_t base4 = ((size_t)b * N_ + i0) * (M_ / 4);
    const f32x4* sp = reinterpret_cast<const f32x4*>(s0) + base4;
    f32x4*       op = reinterpret_cast<f32x4*>(out) + base4;
    #pragma unroll 4
    for (int i = 0; i < ICHUNK; ++i) {
        const float r  = rS[i];
        const f32x4 sv = sp[(size_t)i * (M_ / 4) + t];
        f32x4 o;
        o.x = r * sv.x * c4.x;
        o.y = r * sv.y * c4.y;
        o.z = r * sv.z * c4.z;
        o.w = r * sv.w * c4.w;
        __builtin_nontemporal_store(o, op + (size_t)i * (M_ / 4) + t);
    }
}

// ===========================================================================
extern "C" void kernel_launch(void* const* d_in, const int* in_sizes, int n_in,
                              void* d_out, int out_size, void* d_ws, size_t ws_size,
                              hipStream_t stream)
{
    const float* s0  = (const float*)d_in[0];
    float*       out = (float*)d_out;

    constexpr size_t F16_BYTES = (size_t)B_ * N_ * M_ * 2;       // 64 MiB
    constexpr size_t VEC_BYTES = (size_t)7 * B_ * 1024 * sizeof(float);
    const bool useF16 = ws_size >= F16_BYTES + VEC_BYTES;

    _Float16* sh  = useF16 ? (_Float16*)d_ws : nullptr;
    float*    vec = useF16 ? (float*)((char*)d_ws + F16_BYTES) : (float*)d_ws;

    float* acc[3];
    acc[0]       = vec;
    acc[1]       = acc[0] + B_ * 1024;
    acc[2]       = acc[1] + B_ * 1024;
    float* rbuf0 = acc[2] + B_ * 1024;
    float* rbuf1 = rbuf0 + B_ * 1024;
    float* cbuf0 = rbuf1 + B_ * 1024;
    float* cbuf1 = cbuf0 + B_ * 1024;

    // acc[0] must be zero before kernel 0 accumulates; the rest are zeroed
    // by kernel k for kernel k+1 (acc[(k+1)%3], last read at k-1 -> race-free).
    hipMemsetAsync(acc[0], 0, B_ * 1024 * sizeof(float), stream);

    const dim3 grid(B_ * NCHUNKS);     // 1024 blocks
    const dim3 block(THREADS);

    // k=0 (colsum, r=1): u0 -> acc[0]; zero acc[1]; emit fp16 copy
    if (useF16)
        colsum_conv_kernel<<<grid, block, 0, stream>>>(s0, sh, acc[0], acc[1]);
    else
        colsum_kernel<<<grid, block, 0, stream>>>(s0, nullptr, nullptr,
                                                  rbuf0, acc[0], acc[1], 0);

    // k=1 (rowsum, c1=1/(u0+eps)): c1 -> cbuf0; v1 -> acc[1]; zero acc[2]
    if (useF16)
        rowsum_f16_kernel<<<grid, block, 0, stream>>>(sh, nullptr, acc[0],
                                                      cbuf0, acc[1], acc[2], 1);
    else
        rowsum_kernel<<<grid, block, 0, stream>>>(s0, nullptr, acc[0],
                                                  cbuf0, acc[1], acc[2], 1);

    // k=2 (colsum, r2=1/(v1+eps)): r2 -> rbuf0; u2 -> acc[2]; zero acc[0]
    if (useF16)
        colsum_f16_kernel<<<grid, block, 0, stream>>>(sh, nullptr, acc[1],
                                                      rbuf0, acc[2], acc[0], 1);
    else
        colsum_kernel<<<grid, block, 0, stream>>>(s0, nullptr, acc[1],
                                                  rbuf0, acc[2], acc[0], 1);

    int rIdx = 0, cIdx = 0;   // rbuf0=r2, cbuf0=c1
    for (int k = 3; k <= 14; ++k) {
        float* accR = acc[(k - 1) % 3];
        float* accW = acc[k % 3];
        float* accZ = acc[(k + 1) % 3];
        if (k & 1) {  // rowsum: c_k from cprev + accR
            float* cp = (cIdx == 0) ? cbuf0 : cbuf1;
            float* cn = (cIdx == 0) ? cbuf1 : cbuf0;
            if (useF16)
                rowsum_f16_kernel<<<grid, block, 0, stream>>>(sh, cp, accR, cn, accW, accZ, 2);
            else
                rowsum_kernel<<<grid, block, 0, stream>>>(s0, cp, accR, cn, accW, accZ, 2);
            cIdx ^= 1;
        } else {      // colsum: r_k from rprev + accR
            float* rp = (rIdx == 0) ? rbuf0 : rbuf1;
            float* rn = (rIdx == 0) ? rbuf1 : rbuf0;
            if (useF16)
                colsum_f16_kernel<<<grid, block, 0, stream>>>(sh, rp, accR, rn, accW, accZ, 2);
            else
                colsum_kernel<<<grid, block, 0, stream>>>(s0, rp, accR, rn, accW, accZ, 2);
            rIdx ^= 1;
        }
    }

    // after k=14: u14 in acc[2], r14 in rbuf0 (rIdx=0), c13 in cbuf1 (cIdx=1)
    final_kernel<<<grid, block, 0, stream>>>(
        s0,
        (cIdx == 0) ? cbuf0 : cbuf1,
        acc[14 % 3],
        (rIdx == 0) ? rbuf0 : rbuf1,
        out);
}

// Round 6
// 466.938 us; speedup vs baseline: 2.0234x; 2.0234x over previous
//
#include <hip/hip_runtime.h>

// Sinkhorn [B=32, N=1024, M=1024], 15 alternating normalizations, eps=1e-4.
// Factorized: s_k = diag(r_k) * S0 * diag(c_k); each iteration is one matvec
// with the constant S0 + a tiny vector update folded into the consumer.
// Pass 0 emits an fp16 copy of S0 (64 MiB, L3-resident); middle passes read it.
// NO GLOBAL ATOMICS: column-sum kernels write per-chunk partial vectors to
// upart[b][chunk][:]; the consumer reduces the 32 partials (L2-resident).
// Round-5 counters showed 2M device-scope atomicAdds = 67 MB RMW write
// traffic + 100 us stall per colsum (VALUBusy 1.4%). This removes them.

#define EPSF 1e-4f
constexpr int B_      = 32;
constexpr int N_      = 1024;
constexpr int M_      = 1024;
constexpr int ICHUNK  = 32;            // rows per block
constexpr int NCHUNKS = N_ / ICHUNK;   // 32
constexpr int THREADS = 256;

typedef _Float16 half4v __attribute__((ext_vector_type(4)));
typedef _Float16 half8v __attribute__((ext_vector_type(8)));
typedef float    f32x4  __attribute__((ext_vector_type(4)));

// ===========================================================================
// k=0 (colsum, r=1): partial u0[b][chunk][j] = sum_{i in chunk} s0[b][i][j];
// also emits the fp16 copy. No atomics: plain partial store.
// ===========================================================================
__global__ __launch_bounds__(THREADS)
void colsum_conv_kernel(const float* __restrict__ s0,
                        _Float16* __restrict__ sh,
                        float* __restrict__ upart)
{
    const int bid = blockIdx.x, t = threadIdx.x;
    const int b = bid % B_, chunk = bid / B_;
    const int i0 = chunk * ICHUNK;

    const size_t base4 = ((size_t)b * N_ + i0) * (M_ / 4);
    const f32x4* s4 = reinterpret_cast<const f32x4*>(s0) + base4;
    half4v*      o4 = reinterpret_cast<half4v*>(sh) + base4;

    f32x4 acc = {0.f, 0.f, 0.f, 0.f};
    #pragma unroll 4
    for (int i = 0; i < ICHUNK; ++i) {
        const f32x4 sv = s4[(size_t)i * (M_ / 4) + t];
        acc += sv;
        half4v h;
        h[0] = (_Float16)sv.x; h[1] = (_Float16)sv.y;
        h[2] = (_Float16)sv.z; h[3] = (_Float16)sv.w;
        o4[(size_t)i * (M_ / 4) + t] = h;
    }
    reinterpret_cast<f32x4*>(upart + ((size_t)b * NCHUNKS + chunk) * M_)[t] = acc;
}

// ===========================================================================
// colsum fp16 (even k>=2): upart[b][chunk][j] = sum_{i in chunk} r_k[i]*sh[i][j]
//   r_k = rp/(rp*v+eps); mode 1: rp=1 (k=2), mode 2: rp=rprev.
// Thread t owns cols 4t..4t+3 over all 32 chunk rows -> plain partial store.
// ===========================================================================
__global__ __launch_bounds__(THREADS)
void colsum_f16_kernel(const _Float16* __restrict__ sh,
                       const float* __restrict__ rprev,
                       const float* __restrict__ vacc,
                       float* __restrict__ rout,
                       float* __restrict__ upart,
                       int mode)
{
    __shared__ float rS[ICHUNK];
    const int bid = blockIdx.x, t = threadIdx.x;
    const int b = bid % B_, chunk = bid / B_;
    const int i0 = chunk * ICHUNK;

    if (t < ICHUNK) {
        const int gi = b * N_ + i0 + t;
        const float v  = vacc[gi];
        const float rp = (mode == 1) ? 1.0f : rprev[gi];
        const float r  = rp / (rp * v + EPSF);
        rout[gi] = r;        // (b,i) owned exclusively by this block
        rS[t] = r;
    }
    __syncthreads();

    const half4v* srow = reinterpret_cast<const half4v*>(sh)
                       + ((size_t)b * N_ + i0) * (M_ / 4);
    f32x4 acc = {0.f, 0.f, 0.f, 0.f};
    #pragma unroll 8
    for (int i = 0; i < ICHUNK; ++i) {
        const float  r  = rS[i];                 // LDS broadcast (free)
        const half4v s4 = srow[(size_t)i * (M_ / 4) + t];
        acc.x += r * (float)s4[0]; acc.y += r * (float)s4[1];
        acc.z += r * (float)s4[2]; acc.w += r * (float)s4[3];
    }
    reinterpret_cast<f32x4*>(upart + ((size_t)b * NCHUNKS + chunk) * M_)[t] = acc;
}

// ===========================================================================
// rowsum fp16 (odd k): v[b][i] = sum_j sh[b][i][j] * c_k[b][j]
//   u_j reduced from upart (32 partials, L2-resident); c_k = cp/(cp*u+eps);
//   mode 1: cp=1 (k=1), mode 2: cp=cprev.
// One wave per row, half8 16B loads, c hoisted to registers, shuffle reduce.
// ===========================================================================
__global__ __launch_bounds__(THREADS)
void rowsum_f16_kernel(const _Float16* __restrict__ sh,
                       const float* __restrict__ cprev,
                       const float* __restrict__ upart,
                       float* __restrict__ cout,
                       float* __restrict__ vacc,
                       int mode)
{
    __shared__ float cS[M_];
    const int bid = blockIdx.x, t = threadIdx.x;
    const int b = bid % B_, chunk = bid / B_;
    const int i0 = chunk * ICHUNK;

    {
        // reduce the 32 column-sum partials for this thread's 4 cols
        f32x4 u4 = {0.f, 0.f, 0.f, 0.f};
        const f32x4* up = reinterpret_cast<const f32x4*>(upart + (size_t)b * NCHUNKS * M_);
        #pragma unroll 8
        for (int ch = 0; ch < NCHUNKS; ++ch)
            u4 += up[ch * (M_ / 4) + t];

        f32x4 cp4 = {1.f, 1.f, 1.f, 1.f};
        if (mode != 1)
            cp4 = reinterpret_cast<const f32x4*>(cprev + b * M_)[t];
        f32x4 c4;
        c4.x = cp4.x / (cp4.x * u4.x + EPSF);
        c4.y = cp4.y / (cp4.y * u4.y + EPSF);
        c4.z = cp4.z / (cp4.z * u4.z + EPSF);
        c4.w = cp4.w / (cp4.w * u4.w + EPSF);
        reinterpret_cast<f32x4*>(cS)[t] = c4;
        if (chunk == 0)   // one block per batch persists c_k
            reinterpret_cast<f32x4*>(cout + b * M_)[t] = c4;
    }
    __syncthreads();

    const int wave = t >> 6, lane = t & 63;
    constexpr int RPW = ICHUNK / 4;   // 8 rows per wave

    // hoist c fragments (row-invariant): cols 8*(q*64+lane)..+7
    const f32x4* cS4 = reinterpret_cast<const f32x4*>(cS);
    f32x4 creg[2][2];
    #pragma unroll
    for (int q = 0; q < 2; ++q) {
        creg[q][0] = cS4[2 * (q * 64 + lane)];
        creg[q][1] = cS4[2 * (q * 64 + lane) + 1];
    }

    const half8v* sbase =
        reinterpret_cast<const half8v*>(sh) + (size_t)b * N_ * (M_ / 8);
    #pragma unroll 2
    for (int rw = 0; rw < RPW; ++rw) {
        const int i = i0 + wave * RPW + rw;
        const half8v* row = sbase + (size_t)i * (M_ / 8);
        float sum = 0.f;
        #pragma unroll
        for (int q = 0; q < 2; ++q) {
            const half8v s8 = row[q * 64 + lane];
            sum += (float)s8[0] * creg[q][0].x + (float)s8[1] * creg[q][0].y
                 + (float)s8[2] * creg[q][0].z + (float)s8[3] * creg[q][0].w
                 + (float)s8[4] * creg[q][1].x + (float)s8[5] * creg[q][1].y
                 + (float)s8[6] * creg[q][1].z + (float)s8[7] * creg[q][1].w;
        }
        #pragma unroll
        for (int off = 32; off > 0; off >>= 1)
            sum += __shfl_down(sum, off, 64);
        if (lane == 0)
            vacc[b * N_ + i] = sum;   // exclusive per (b,i): plain store
    }
}

// ===========================================================================
// fp32 fallback kernels (used only if ws_size can't hold the fp16 copy)
// ===========================================================================
__global__ __launch_bounds__(THREADS)
void colsum_kernel(const float* __restrict__ s0,
                   const float* __restrict__ rprev,
                   const float* __restrict__ vacc,
                   float* __restrict__ rout,
                   float* __restrict__ upart,
                   int mode)
{
    __shared__ float rS[ICHUNK];
    const int bid = blockIdx.x, t = threadIdx.x;
    const int b = bid % B_, chunk = bid / B_;
    const int i0 = chunk * ICHUNK;

    if (t < ICHUNK) {
        const int gi = b * N_ + i0 + t;
        float r;
        if (mode == 0) r = 1.0f;
        else {
            const float v  = vacc[gi];
            const float rp = (mode == 1) ? 1.0f : rprev[gi];
            r = rp / (rp * v + EPSF);
            rout[gi] = r;
        }
        rS[t] = r;
    }
    __syncthreads();

    const f32x4* srow =
        reinterpret_cast<const f32x4*>(s0) + ((size_t)b * N_ + i0) * (M_ / 4);
    f32x4 acc = {0.f, 0.f, 0.f, 0.f};
    #pragma unroll 8
    for (int i = 0; i < ICHUNK; ++i) {
        const float r  = rS[i];
        const f32x4 sv = srow[(size_t)i * (M_ / 4) + t];
        acc.x += r * sv.x; acc.y += r * sv.y;
        acc.z += r * sv.z; acc.w += r * sv.w;
    }
    reinterpret_cast<f32x4*>(upart + ((size_t)b * NCHUNKS + chunk) * M_)[t] = acc;
}

__global__ __launch_bounds__(THREADS)
void rowsum_kernel(const float* __restrict__ s0,
                   const float* __restrict__ cprev,
                   const float* __restrict__ upart,
                   float* __restrict__ cout,
                   float* __restrict__ vacc,
                   int mode)
{
    __shared__ float cS[M_];
    const int bid = blockIdx.x, t = threadIdx.x;
    const int b = bid % B_, chunk = bid / B_;
    const int i0 = chunk * ICHUNK;

    {
        f32x4 u4 = {0.f, 0.f, 0.f, 0.f};
        const f32x4* up = reinterpret_cast<const f32x4*>(upart + (size_t)b * NCHUNKS * M_);
        #pragma unroll 8
        for (int ch = 0; ch < NCHUNKS; ++ch)
            u4 += up[ch * (M_ / 4) + t];

        f32x4 cp4 = {1.f, 1.f, 1.f, 1.f};
        if (mode != 1)
            cp4 = reinterpret_cast<const f32x4*>(cprev + b * M_)[t];
        f32x4 c4;
        c4.x = cp4.x / (cp4.x * u4.x + EPSF);
        c4.y = cp4.y / (cp4.y * u4.y + EPSF);
        c4.z = cp4.z / (cp4.z * u4.z + EPSF);
        c4.w = cp4.w / (cp4.w * u4.w + EPSF);
        reinterpret_cast<f32x4*>(cS)[t] = c4;
        if (chunk == 0)
            reinterpret_cast<f32x4*>(cout + b * M_)[t] = c4;
    }
    __syncthreads();

    const int wave = t >> 6, lane = t & 63;
    constexpr int RPW = ICHUNK / 4;
    const f32x4* cS4 = reinterpret_cast<const f32x4*>(cS);
    f32x4 creg[4];
    #pragma unroll
    for (int q = 0; q < 4; ++q)
        creg[q] = cS4[q * 64 + lane];

    const f32x4* sbase =
        reinterpret_cast<const f32x4*>(s0) + (size_t)b * N_ * (M_ / 4);
    for (int rw = 0; rw < RPW; ++rw) {
        const int i = i0 + wave * RPW + rw;
        const f32x4* row = sbase + (size_t)i * (M_ / 4);
        float sum = 0.f;
        #pragma unroll
        for (int q = 0; q < 4; ++q) {
            const f32x4 sv = row[q * 64 + lane];
            sum += sv.x * creg[q].x + sv.y * creg[q].y +
                   sv.z * creg[q].z + sv.w * creg[q].w;
        }
        #pragma unroll
        for (int off = 32; off > 0; off >>= 1)
            sum += __shfl_down(sum, off, 64);
        if (lane == 0)
            vacc[b * N_ + i] = sum;
    }
}

// ===========================================================================
// final: out[b][i][j] = r14[b][i] * s0[b][i][j] * c15[b][j]  (fp32 S0)
//   u14 reduced from upart; c15 = c13/(c13*u14+eps). NT stores (never re-read).
// ===========================================================================
__global__ __launch_bounds__(THREADS)
void final_kernel(const float* __restrict__ s0,
                  const float* __restrict__ cprev,   // c13
                  const float* __restrict__ upart,   // u14 partials
                  const float* __restrict__ rbuf,    // r14
                  float* __restrict__ out)
{
    __shared__ float rS[ICHUNK];
    const int bid = blockIdx.x, t = threadIdx.x;
    const int b = bid % B_, chunk = bid / B_;
    const int i0 = chunk * ICHUNK;

    f32x4 u4 = {0.f, 0.f, 0.f, 0.f};
    const f32x4* up = reinterpret_cast<const f32x4*>(upart + (size_t)b * NCHUNKS * M_);
    #pragma unroll 8
    for (int ch = 0; ch < NCHUNKS; ++ch)
        u4 += up[ch * (M_ / 4) + t];

    const f32x4 cp4 = reinterpret_cast<const f32x4*>(cprev + b * M_)[t];
    f32x4 c4;
    c4.x = cp4.x / (cp4.x * u4.x + EPSF);
    c4.y = cp4.y / (cp4.y * u4.y + EPSF);
    c4.z = cp4.z / (cp4.z * u4.z + EPSF);
    c4.w = cp4.w / (cp4.w * u4.w + EPSF);

    if (t < ICHUNK) rS[t] = rbuf[b * N_ + i0 + t];
    __syncthreads();

    const size_t base4 = ((size_t)b * N_ + i0) * (M_ / 4);
    const f32x4* sp = reinterpret_cast<const f32x4*>(s0) + base4;
    f32x4*       op = reinterpret_cast<f32x4*>(out) + base4;
    #pragma unroll 4
    for (int i = 0; i < ICHUNK; ++i) {
        const float r  = rS[i];
        const f32x4 sv = sp[(size_t)i * (M_ / 4) + t];
        f32x4 o;
        o.x = r * sv.x * c4.x;
        o.y = r * sv.y * c4.y;
        o.z = r * sv.z * c4.z;
        o.w = r * sv.w * c4.w;
        __builtin_nontemporal_store(o, op + (size_t)i * (M_ / 4) + t);
    }
}

// ===========================================================================
extern "C" void kernel_launch(void* const* d_in, const int* in_sizes, int n_in,
                              void* d_out, int out_size, void* d_ws, size_t ws_size,
                              hipStream_t stream)
{
    const float* s0  = (const float*)d_in[0];
    float*       out = (float*)d_out;

    constexpr size_t F16_BYTES = (size_t)B_ * N_ * M_ * 2;             // 64 MiB
    constexpr size_t UPART_FLOATS = (size_t)B_ * NCHUNKS * M_;         // 1M floats
    constexpr size_t VEC_BYTES = (UPART_FLOATS + 5 * (size_t)B_ * 1024) * sizeof(float);
    const bool useF16 = ws_size >= F16_BYTES + VEC_BYTES;

    _Float16* sh  = useF16 ? (_Float16*)d_ws : nullptr;
    float*    vec = useF16 ? (float*)((char*)d_ws + F16_BYTES) : (float*)d_ws;

    float* upart = vec;
    float* vacc  = upart + UPART_FLOATS;
    float* rbuf0 = vacc  + B_ * 1024;
    float* rbuf1 = rbuf0 + B_ * 1024;
    float* cbuf0 = rbuf1 + B_ * 1024;
    float* cbuf1 = cbuf0 + B_ * 1024;

    const dim3 grid(B_ * NCHUNKS);     // 1024 blocks
    const dim3 block(THREADS);

    // k=0 (colsum, r=1): u0 partials -> upart; emit fp16 copy
    if (useF16)
        colsum_conv_kernel<<<grid, block, 0, stream>>>(s0, sh, upart);
    else
        colsum_kernel<<<grid, block, 0, stream>>>(s0, nullptr, nullptr,
                                                  nullptr, upart, 0);

    // k=1 (rowsum, c1=1/(u0+eps)): c1 -> cbuf0; v1 -> vacc
    if (useF16)
        rowsum_f16_kernel<<<grid, block, 0, stream>>>(sh, nullptr, upart,
                                                      cbuf0, vacc, 1);
    else
        rowsum_kernel<<<grid, block, 0, stream>>>(s0, nullptr, upart,
                                                  cbuf0, vacc, 1);

    // k=2 (colsum, r2=1/(v1+eps)): r2 -> rbuf0; u2 partials -> upart
    if (useF16)
        colsum_f16_kernel<<<grid, block, 0, stream>>>(sh, nullptr, vacc,
                                                      rbuf0, upart, 1);
    else
        colsum_kernel<<<grid, block, 0, stream>>>(s0, nullptr, vacc,
                                                  rbuf0, upart, 1);

    int rIdx = 0, cIdx = 0;   // rbuf0=r2, cbuf0=c1
    for (int k = 3; k <= 14; ++k) {
        if (k & 1) {  // rowsum: c_k from cprev + upart
            float* cp = (cIdx == 0) ? cbuf0 : cbuf1;
            float* cn = (cIdx == 0) ? cbuf1 : cbuf0;
            if (useF16)
                rowsum_f16_kernel<<<grid, block, 0, stream>>>(sh, cp, upart, cn, vacc, 2);
            else
                rowsum_kernel<<<grid, block, 0, stream>>>(s0, cp, upart, cn, vacc, 2);
            cIdx ^= 1;
        } else {      // colsum: r_k from rprev + vacc
            float* rp = (rIdx == 0) ? rbuf0 : rbuf1;
            float* rn = (rIdx == 0) ? rbuf1 : rbuf0;
            if (useF16)
                colsum_f16_kernel<<<grid, block, 0, stream>>>(sh, rp, vacc, rn, upart, 2);
            else
                colsum_kernel<<<grid, block, 0, stream>>>(s0, rp, vacc, rn, upart, 2);
            rIdx ^= 1;
        }
    }

    // after k=14: u14 partials in upart, r14 in rbuf[rIdx], c13 in cbuf[cIdx]
    final_kernel<<<grid, block, 0, stream>>>(
        s0,
        (cIdx == 0) ? cbuf0 : cbuf1,
        upart,
        (rIdx == 0) ? rbuf0 : rbuf1,
        out);
}